// Round 12
// baseline (583.497 us; speedup 1.0000x reference)
//
#include <hip/hip_runtime.h>

// ---------------------------------------------------------------------------
// GCN forward, reassociated: per layer h = relu( (A_hat h) W + b ).
// R24: split-row gather (divergence halving) + deg-precompute (kills scale_x).
// Ladder recap (same gather loop, same ~195MB FETCH):
//   R17 1 wave/tile: 80us | R22 2: 72.5 | R23 4: 68.7, 3.2 TB/s.
// Occupancy stayed ~12 waves/CU throughout -> gains were DIVERGENCE cuts
// (block time = max(nb) over rows in flight). Final rung: block = 512 thr,
// 32 groups; group (row, half) gathers half the row's 8-edge batches;
// halves-1 write f32 partials to LDS, halves-0 combine+scale+write A-tile.
// Block gather time: max(nb over 16 rows) -> ~max/2.
// Layer byte-floor: 220MB @ 3.32 TB/s (R12's best measured rate) = 66us.
// Non-layer: scale_x (51.2MB r+w) removed — count_deg kernel computes
// degrees BEFORE setup_all, and the x-cast applies dinv inline.
// Kept: packed pairs, CHUNK 2048, unpadded CSR, pre-scaled S = dinv*h,
// epilogue folds bias+relu+output-dinv, layer-4 fused head dot.
// NOTE: harness delivers int32 edge_index/batch.
// ---------------------------------------------------------------------------

constexpr int D = 128;
constexpr int NGRAPH = 512;
constexpr int CHUNK = 2048;       // edges per scatter block
constexpr int BSH = 9;            // 512 nodes per bucket
constexpr int OP = 136;           // out-tile pitch (ushorts): 272B, 16B-aligned rows

typedef __attribute__((ext_vector_type(8))) short bf16x8;
typedef __attribute__((ext_vector_type(4))) float f32x4;
typedef int i32x4u __attribute__((ext_vector_type(4), aligned(4)));

__device__ __forceinline__ float bf2f(unsigned short b) {
    return __uint_as_float(((unsigned int)b) << 16);
}
__device__ __forceinline__ unsigned short f2bf(float f) {   // round-to-nearest-even
    unsigned int u = __float_as_uint(f);
    u += 0x7FFFu + ((u >> 16) & 1u);
    return (unsigned short)(u >> 16);
}

// per-node in-degree via global atomics (L2-resident counters)
__global__ __launch_bounds__(256) void count_deg(const int* __restrict__ ec, int E,
                                                 int* __restrict__ deg) {
    int i = blockIdx.x * 256 + threadIdx.x;
    const int stride = gridDim.x * 256;
    for (; i < E; i += stride) atomicAdd(&deg[ec[i]], 1);
}

// merged setup: [0,CB) cast x -> dinv-scaled bf16 (S = dinv*x) |
// [CB,CB+256) cast W -> transposed bf16 Wt | [CB+256,...) bucket histogram.
__global__ __launch_bounds__(256) void setup_all(
        const float4* __restrict__ x4, ushort4* __restrict__ hb, int n4, int CB,
        const float* __restrict__ W, unsigned short* __restrict__ Wt,
        const int* __restrict__ ec, int E, int* __restrict__ bucketCnt,
        const int* __restrict__ deg) {
    __shared__ int h[256];
    const int t = threadIdx.x;
    const int b = blockIdx.x;
    if (b < CB) {
        int i = b * 256 + t;
        if (i < n4) {
            const int node = i >> 5;              // 32 float4 per row
            const float dv = rsqrtf((float)deg[node] + 1.0f);
            float4 v = x4[i];
            ushort4 o;
            o.x = f2bf(v.x * dv); o.y = f2bf(v.y * dv);
            o.z = f2bf(v.z * dv); o.w = f2bf(v.w * dv);
            hb[i] = o;
        }
    } else if (b < CB + 256) {
        int idx = (b - CB) * 256 + t;      // 4*128*128 = 65536 elems
        int i = idx >> 14;
        int rem = idx & 16383;
        int k = rem >> 7, c = rem & 127;
        Wt[(i << 14) + c * 128 + k] = f2bf(W[idx]);
    } else {
        h[t] = 0;
        __syncthreads();
        const int e0 = (b - CB - 256) * CHUNK;
        const int cnt = min(CHUNK, E - e0);
        for (int i = t; i < cnt; i += 256) atomicAdd(&h[ec[e0 + i] >> BSH], 1);
        __syncthreads();
        if (h[t]) atomicAdd(&bucketCnt[t], h[t]);
    }
}

// exclusive scan over 256 bucket counts -> bucketBase, globCursor
__global__ __launch_bounds__(256) void bucket_scan(const int* __restrict__ bucketCnt,
                                                   int* __restrict__ bucketBase,
                                                   int* __restrict__ globCursor) {
    __shared__ int s[256];
    const int t = threadIdx.x;
    int v = bucketCnt[t];
    s[t] = v; __syncthreads();
    for (int off = 1; off < 256; off <<= 1) {
        int x = (t >= off) ? s[t - off] : 0;
        __syncthreads();
        s[t] += x;
        __syncthreads();
    }
    int excl = s[t] - v;
    bucketBase[t] = excl;
    globCursor[t] = excl;
}

// scatter packed (r<<9 | c&511) into bucket-grouped array, LDS-staged
__global__ __launch_bounds__(256) void scatter_pairs(const int* __restrict__ er,
                                                     const int* __restrict__ ec, int E,
                                                     int* __restrict__ globCursor,
                                                     int* __restrict__ pairs) {
    __shared__ int h[256], lbase[256], cur[256], segd[256], s[256];
    __shared__ int stage[CHUNK];
    __shared__ unsigned char sb[CHUNK];
    const int t = threadIdx.x;
    const int e0 = blockIdx.x * CHUNK;
    const int cnt = min(CHUNK, E - e0);

    h[t] = 0;
    __syncthreads();
    for (int i = t; i < cnt; i += 256) atomicAdd(&h[ec[e0 + i] >> BSH], 1);
    __syncthreads();
    int v = h[t];
    s[t] = v; __syncthreads();
    for (int off = 1; off < 256; off <<= 1) {
        int x = (t >= off) ? s[t - off] : 0;
        __syncthreads();
        s[t] += x;
        __syncthreads();
    }
    lbase[t] = s[t] - v;
    cur[t] = s[t] - v;
    segd[t] = atomicAdd(&globCursor[t], v) - lbase[t];
    __syncthreads();
    for (int i = t; i < cnt; i += 256) {
        int c = ec[e0 + i];
        int b = c >> BSH;
        int p = atomicAdd(&cur[b], 1);
        stage[p] = (er[e0 + i] << BSH) | (c & 511);   // packed pair
        sb[p] = (unsigned char)b;
    }
    __syncthreads();
    for (int i = t; i < cnt; i += 256) {
        int b = sb[i];
        pairs[segd[b] + i] = stage[i];
    }
}

// one block per bucket. LDS hist+scan -> rowptr, dinv, slot fill. Unpadded.
__global__ __launch_bounds__(256) void fill_csr(const int* __restrict__ pairs,
                                                const int* __restrict__ bucketBase,
                                                const int* __restrict__ bucketCnt,
                                                int N, int E, int NBUCK,
                                                int* __restrict__ rowptr,
                                                float* __restrict__ dinv,
                                                int* __restrict__ srcs) {
    __shared__ int hist[512], lofs[512], s[256];
    const int t = threadIdx.x;
    const int b = blockIdx.x;
    const int c0 = b << BSH;
    const int base = bucketBase[b];
    const int cnt = bucketCnt[b];
    const int* pp = pairs + base;

    hist[t] = 0; hist[t + 256] = 0;
    __syncthreads();
    for (int i = t; i < cnt; i += 256) atomicAdd(&hist[pp[i] & 511], 1);
    __syncthreads();
    int a0 = hist[2 * t], a1 = hist[2 * t + 1];
    s[t] = a0 + a1; __syncthreads();
    for (int off = 1; off < 256; off <<= 1) {
        int x = (t >= off) ? s[t - off] : 0;
        __syncthreads();
        s[t] += x;
        __syncthreads();
    }
    int excl = s[t] - (a0 + a1);
    lofs[2 * t] = excl;
    lofs[2 * t + 1] = excl + a0;
    __syncthreads();
    const int nn = min(512, N - c0);
    for (int i = t; i < nn; i += 256) {
        rowptr[c0 + i] = base + lofs[i];
        dinv[c0 + i] = rsqrtf((float)hist[i] + 1.0f);
    }
    if (b == NBUCK - 1 && t == 0) rowptr[N] = E;
    __syncthreads();
    for (int i = t; i < cnt; i += 256) {
        int pr = pp[i];
        int p = atomicAdd(&lofs[pr & 511], 1);
        srcs[base + p] = pr >> BSH;
    }
}

// ---------------------------------------------------------------------------
// Fused layer: 512-thread block (8 waves) per 16-row tile, SPLIT-ROW gather.
// Phase A: 32 sixteen-lane groups; grp = tid>>4; row rt = grp&15, half
//   hf = grp>>4. Half hf gathers batch range [hf?nb0:0, hf?nb:nb0) of its
//   row (nb0 = ceil(nb/2)); half 0 also adds the self term. Halves-1 write
//   f32 partials to LDS F; barrier; halves-0 combine, scale by dinv[row],
//   write bf16 into the xor-swizzled A-tile. Block gather time ~max(nb)/2
//   over the 16 rows (was max(nb) in R23). Inner loop = proven masked
//   8-edge batches (R17/R22/R23), untouched.
// Phase B: barrier; all 8 waves load the same A-frags; barrier; wave w
//   computes column-tile ct = w. Epilogue folds bias+relu+output-dinv into
//   the shared out tile (pitch OP); barrier; 16B readback+stores (tid<256).
//   Layer 4 (writeDots): intra-wave shfl reduce + 8-wave LDS reduce (in F).
// C/D: col=lane&15, row=(lane>>4)*4+reg (verified mapping).
// ---------------------------------------------------------------------------
__global__ __launch_bounds__(512, 4) void layer_fused(
        const int* __restrict__ rowptr, const int* __restrict__ srcs,
        const float* __restrict__ dinv, const unsigned short* __restrict__ H,
        const unsigned short* __restrict__ Wt, const float* __restrict__ bias,
        unsigned short* __restrict__ Hn, float* __restrict__ dots,
        const float* __restrict__ Wl, int N, int writeDots) {
    __shared__ __align__(16) unsigned short U[16 * OP];   // 4.25 KB
    __shared__ float F[16][128];                          // 8 KB partials
    const int tid = threadIdx.x;         // 0..511
    const int wave = tid >> 6;           // 0..7
    const int lane = tid & 63;
    const int row16 = lane & 15;
    const int quad = lane >> 4;          // 0..3
    const int grp = tid >> 4;            // 0..31
    const int rt = grp & 15;             // local row 0..15
    const int hf = grp >> 4;             // half 0/1
    const int gl = tid & 15;             // 16B chunk this lane owns
    const int r0 = blockIdx.x * 16;
    const bf16x8* H8 = (const bf16x8*)H;     // 16 chunks (16B) per row

    // ---- phase A: split-row gather ----
    {
        const int row = r0 + rt;
        float acc[8] = {0.f, 0.f, 0.f, 0.f, 0.f, 0.f, 0.f, 0.f};
        if (row < N) {
            const int j0 = rowptr[row];
            const int neF = rowptr[row + 1] - j0;
            const int nbF = (neF + 7) >> 3;
            const int nb0 = (nbF + 1) >> 1;           // batches for half 0
            const int bs = hf ? nb0 : 0;
            const int be = hf ? nbF : nb0;
            const int j = j0 + bs * 8;
            const int ne = min(neF, be * 8) - bs * 8; // local edge count
            if (hf == 0) {   // self-loop term (pre-scaled S)
                bf16x8 hv = H8[(size_t)row * 16 + gl];
#pragma unroll
                for (int k = 0; k < 8; ++k) acc[k] = bf2f((unsigned short)hv[k]);
            }
            const int nb = be - bs;
            if (ne > 0 && nb > 0) {
                i32x4u sA0, sA1, sB0, sB1;
                {   // srcs(0); srcs(1) issued BEFORE h(0)
                    const i32x4u* sp = (const i32x4u*)(srcs + j);
                    sA0 = sp[0]; sA1 = sp[1];
                }
                if (nb > 1) {
                    const i32x4u* sp = (const i32x4u*)(srcs + j + 8);
                    sB0 = sp[0]; sB1 = sp[1];
                }
                bf16x8 hc[8], hn[8];
#pragma unroll
                for (int t = 0; t < 8; ++t) {       // issue h(0)
                    int idx = (t < 4) ? sA0[t] : sA1[t - 4];
                    int rr = (t < ne) ? idx : row;
                    hc[t] = H8[(size_t)rr * 16 + gl];
                }
#pragma unroll 1
                for (int b = 0; b < nb; ++b) {
                    if (b + 1 < nb) {
                        const int remn = ne - (b + 1) * 8;
                        int rn[8];
#pragma unroll
                        for (int t = 0; t < 8; ++t) {   // waits srcs(b+1) only
                            int idx = (t < 4) ? sB0[t] : sB1[t - 4];
                            rn[t] = (t < remn) ? idx : row;
                        }
                        if (b + 2 < nb) {               // srcs(b+2) BEFORE h(b+1)
                            const i32x4u* sp = (const i32x4u*)(srcs + j + (b + 2) * 8);
                            sB0 = sp[0]; sB1 = sp[1];
                        }
#pragma unroll
                        for (int t = 0; t < 8; ++t)     // issue h(b+1)
                            hn[t] = H8[(size_t)rn[t] * 16 + gl];
                    }
                    // consume h(b); weight from remaining count
                    const int rem = ne - b * 8;
#pragma unroll
                    for (int t = 0; t < 8; ++t) {
                        const float w = (t < rem) ? 1.f : 0.f;
#pragma unroll
                        for (int k = 0; k < 8; ++k)
                            acc[k] = fmaf(w, bf2f((unsigned short)hc[t][k]), acc[k]);
                    }
#pragma unroll
                    for (int t = 0; t < 8; ++t) hc[t] = hn[t];
                }
            }
        }
        if (hf == 1) {   // publish partial
#pragma unroll
            for (int k = 0; k < 8; ++k) F[rt][gl * 8 + k] = acc[k];
        }
        __syncthreads();
        if (hf == 0) {   // combine, scale, write swizzled A-tile row
            const float sn = (row < N) ? dinv[row] : 0.f;
            bf16x8 o;
#pragma unroll
            for (int k = 0; k < 8; ++k)
                o[k] = (short)f2bf(sn * (acc[k] + F[rt][gl * 8 + k]));
            *(bf16x8*)(U + rt * 128 + ((gl ^ rt) << 3)) = o;
        }
    }
    __syncthreads();

    // ---- phase B: all waves load the same A fragments ----
    bf16x8 a0[4];
#pragma unroll
    for (int kc = 0; kc < 4; ++kc) {
        const int ph = (kc * 4 + quad) ^ row16;
        a0[kc] = *(const bf16x8*)(U + row16 * 128 + ph * 8);
    }
    __syncthreads();   // U is now reused as the out tile (pitch OP)

    // dinv of output rows (pre-scale stored features); not needed for dots
    float dv4[4];
    if (!writeDots) {
#pragma unroll
        for (int i = 0; i < 4; ++i) {
            int ra = r0 + quad * 4 + i;
            dv4[i] = (ra < N) ? dinv[ra] : 0.f;
        }
    }

    // wave w handles column-tile ct = w
    float rd[4] = {0.f, 0.f, 0.f, 0.f};
    {
        const int ct = wave;
        const int col = ct * 16 + row16;
        const bf16x8* wc = (const bf16x8*)(Wt + (size_t)col * 128);
        f32x4 acc0 = {0.f, 0.f, 0.f, 0.f};
#pragma unroll
        for (int kc = 0; kc < 4; ++kc) {
            const bf16x8 wf = wc[kc * 4 + quad];
            acc0 = __builtin_amdgcn_mfma_f32_16x16x32_bf16(a0[kc], wf, acc0, 0, 0, 0);
        }
        const float bv = bias[col];
        if (writeDots) {
            const float wl = Wl[col];
#pragma unroll
            for (int i = 0; i < 4; ++i) rd[i] += fmaxf(acc0[i] + bv, 0.f) * wl;
        } else {
#pragma unroll
            for (int i = 0; i < 4; ++i)
                U[(quad * 4 + i) * OP + col] = f2bf(dv4[i] * fmaxf(acc0[i] + bv, 0.f));
        }
    }

    if (writeDots) {
        // intra-wave: sum over the 16 cols of this ct
#pragma unroll
        for (int m = 1; m < 16; m <<= 1)
#pragma unroll
            for (int i = 0; i < 4; ++i) rd[i] += __shfl_xor(rd[i], m, 64);
        // cross-wave: partials via F (float scratch)
        float* R = &F[0][0];
        __syncthreads();          // F free (phase A done)
        if (row16 == 0) {
#pragma unroll
            for (int i = 0; i < 4; ++i) R[wave * 16 + quad * 4 + i] = rd[i];
        }
        __syncthreads();
        if (tid < 16) {
            float s = 0.f;
#pragma unroll
            for (int w = 0; w < 8; ++w) s += R[w * 16 + tid];
            dots[r0 + tid] = s;
        }
    } else {
        __syncthreads();
        // coalesced readback + store: 256 16B chunks, tid<256 do 1 each
        if (tid < 256) {
            int row = tid >> 4, c8 = tid & 15;
            bf16x8 v = *(const bf16x8*)(U + row * OP + c8 * 8);
            *(bf16x8*)(Hn + (size_t)(r0 + row) * 128 + c8 * 8) = v;
        }
    }
}

// one block per graph: binary-search node range in sorted batch, mean, +bl
__global__ __launch_bounds__(256) void pool_graphs(const float* __restrict__ dots,
                                                   const int* __restrict__ batch, int N,
                                                   const float* __restrict__ bl,
                                                   float* __restrict__ out) {
    __shared__ int bounds[2];
    __shared__ float red[4];
    const int g = blockIdx.x;
    const int t = threadIdx.x;
    if (t < 2) {
        int key = g + t;             // lower_bound(batch, key)
        int lo = 0, hi = N;
        while (lo < hi) {
            int mid = (lo + hi) >> 1;
            if (batch[mid] < key) lo = mid + 1; else hi = mid;
        }
        bounds[t] = lo;
    }
    __syncthreads();
    const int lo = bounds[0], hi = bounds[1];
    float s = 0.f;
    for (int i = lo + t; i < hi; i += 256) s += dots[i];
#pragma unroll
    for (int off = 32; off > 0; off >>= 1) s += __shfl_down(s, off, 64);
    if ((t & 63) == 0) red[t >> 6] = s;
    __syncthreads();
    if (t == 0) {
        float tot = red[0] + red[1] + red[2] + red[3];
        int cnt = hi - lo;
        out[g] = tot / (float)(cnt > 0 ? cnt : 1) + bl[0];
    }
}

extern "C" void kernel_launch(void* const* d_in, const int* in_sizes, int n_in,
                              void* d_out, int out_size, void* d_ws, size_t ws_size,
                              hipStream_t stream) {
    const float* x     = (const float*)d_in[0];
    const int*   eidx  = (const int*)d_in[1];    // int32 (harness converts int64)
    const int*   batch = (const int*)d_in[2];
    const float* Ws    = (const float*)d_in[3];
    const float* bs    = (const float*)d_in[4];
    const float* Wl    = (const float*)d_in[5];
    const float* bl    = (const float*)d_in[6];
    (void)n_in; (void)out_size;

    const int N = in_sizes[0] / D;
    const int E = in_sizes[1] / 2;
    const int* er = eidx;       // sources
    const int* ec = eidx + E;   // targets
    const int NBUCK = (N + 511) >> BSH;          // 512-node buckets (<= 256)
    const int NCHUNK = (E + CHUNK - 1) / CHUNK;

    // ---- workspace carve ----
    const int Npad = (N + 127) & ~127;
    const size_t hBytes = (size_t)Npad * D * sizeof(unsigned short); // 25.6 MB bf16
    auto al = [](size_t v) { return (v + 255) & ~(size_t)255; };
    char* base = (char*)d_ws;
    size_t off = 0;

    unsigned short* Hb0 = (unsigned short*)base; off = al(hBytes);
    int* bucketCnt  = (int*)(base + off);
    int* globCursor = bucketCnt + 256;
    off = al(off + 512 * sizeof(int));
    int*   bucketBase = (int*)(base + off);  off = al(off + 256 * sizeof(int));
    float* dinv   = (float*)(base + off);    off = al(off + (size_t)Npad * sizeof(float));
    float* dots   = (float*)(base + off);    off = al(off + (size_t)Npad * sizeof(float));
    int*   deg    = (int*)(base + off);      off = al(off + (size_t)Npad * sizeof(int));
    int*   rowptr = (int*)(base + off);      off = al(off + (size_t)(Npad + 64) * sizeof(int));
    int*   srcs   = (int*)(base + off);      off = al(off + ((size_t)E + 64) * sizeof(int));
    unsigned short* Wt = (unsigned short*)(base + off);   off = al(off + 4 * 128 * 128 * sizeof(unsigned short));

    // second bf16 buffer: in ws if it fits, else reuse x's 51.2 MB input buffer
    // (Npad*256B <= N*512B, so the alias stays in-bounds). pairs aliases Hb1:
    // CSR build completes before layer-1 gemm writes Hb1 (same stream).
    const bool twoBuf = ws_size >= off + hBytes;
    unsigned short* Hb1 = twoBuf ? (unsigned short*)(base + off)
                                 : (unsigned short*)d_in[0];
    int* pairs = (int*)Hb1;
    unsigned short* hb[2] = { Hb0, Hb1 };

    // ---- setup: zero counters; degrees; merged scaled-cast | W | hist ----
    hipMemsetAsync(bucketCnt, 0, 256 * sizeof(int), stream);
    hipMemsetAsync(deg, 0, (size_t)Npad * sizeof(int), stream);
    count_deg<<<min((E + 255) / 256, 2048), 256, 0, stream>>>(ec, E, deg);
    const int n4 = N * D / 4;
    const int CB = (n4 + 255) / 256;
    setup_all<<<CB + 256 + NCHUNK, 256, 0, stream>>>((const float4*)x, (ushort4*)Hb0,
                                                     n4, CB, Ws, Wt, ec, E, bucketCnt,
                                                     deg);

    // ---- binned CSR build (once; reused by all 4 layers) ----
    bucket_scan<<<1, 256, 0, stream>>>(bucketCnt, bucketBase, globCursor);
    scatter_pairs<<<NCHUNK, 256, 0, stream>>>(er, ec, E, globCursor, pairs);
    fill_csr<<<NBUCK, 256, 0, stream>>>(pairs, bucketBase, bucketCnt, N, E, NBUCK,
                                        rowptr, dinv, srcs);

    // ---- 4 fused layers: aggregate -> LDS A-tile -> MFMA (-> head dot) ----
    for (int i = 0; i < 4; ++i) {
        const unsigned short* Hc = hb[i & 1];
        unsigned short* Hn = hb[(i + 1) & 1];
        layer_fused<<<Npad / 16, 512, 0, stream>>>(rowptr, srcs, dinv, Hc,
                                                   Wt + (size_t)i * D * D,
                                                   bs + (size_t)i * D, Hn, dots, Wl,
                                                   N, (i == 3) ? 1 : 0);
    }

    // ---- mean pool (+bl) over fused per-node dots ----
    pool_graphs<<<NGRAPH, 256, 0, stream>>>(dots, batch, N, bl, (float*)d_out);
}

// Round 13
// 447.612 us; speedup vs baseline: 1.3036x; 1.3036x over previous
//
#include <hip/hip_runtime.h>

// ---------------------------------------------------------------------------
// GCN forward, reassociated: per layer h = relu( (A_hat h) W + b ).
// R25 = exact revert to R23 (best measured: 452.5 us total, 68.7 us/layer).
// R24 post-mortem: split-row gather put 3 block-wide barriers in an 8-wave
// block at ~1.6 blocks/CU -> barrier drained the CU's gather pipe (R13's
// mistake at larger scale); BW 3.2->2.1 TB/s, +6x LDS bank conflicts from
// the partial buffer. Also moot on arithmetic: at 3.2/3.32 TB/s of the
// measured service wall, divergence cuts cap at ~4%. deg-precompute setup
// also cost ~+43 us unexplained. Both reverted.
// R23 structure: 4 waves per 16-row tile -> 1 row per 16-lane group (chain
// floor). Wave ladder R17(1w)=80 -> R22(2w)=72.5 -> R23(4w)=68.7 us at
// 3.2 TB/s; layer floor = 214.5MB @ 3.32 TB/s = 64.6 us (within ~5%).
// Phase B: wave w computes column-tiles ct = 2w,2w+1 (disjoint out cols,
// shared LDS A-frags); layer-4 head dot: intra-wave shfl + 4-wave LDS
// reduce. Gather loop = proven masked 8-edge batches.
// Kept: dedicated scale_x, packed pairs, CHUNK 2048, unpadded CSR.
// All layers pre-scaled (S = dinv*h). Epilogue folds bias+relu+output-dinv.
// NOTE: harness delivers int32 edge_index/batch.
// ---------------------------------------------------------------------------

constexpr int D = 128;
constexpr int NGRAPH = 512;
constexpr int CHUNK = 2048;       // edges per scatter block
constexpr int BSH = 9;            // 512 nodes per bucket
constexpr int OP = 136;           // out-tile pitch (ushorts): 272B, 16B-aligned rows

typedef __attribute__((ext_vector_type(8))) short bf16x8;
typedef __attribute__((ext_vector_type(4))) float f32x4;
typedef int i32x4u __attribute__((ext_vector_type(4), aligned(4)));

__device__ __forceinline__ float bf2f(unsigned short b) {
    return __uint_as_float(((unsigned int)b) << 16);
}
__device__ __forceinline__ unsigned short f2bf(float f) {   // round-to-nearest-even
    unsigned int u = __float_as_uint(f);
    u += 0x7FFFu + ((u >> 16) & 1u);
    return (unsigned short)(u >> 16);
}

// merged independent setup: [0,CB) cast x->bf16 | [CB,CB+256) cast W ->
// transposed bf16 Wt | [CB+256, ...) per-chunk bucket histogram.
__global__ __launch_bounds__(256) void setup_all(
        const float4* __restrict__ x4, ushort4* __restrict__ hb, int n4, int CB,
        const float* __restrict__ W, unsigned short* __restrict__ Wt,
        const int* __restrict__ ec, int E, int* __restrict__ bucketCnt) {
    __shared__ int h[256];
    const int t = threadIdx.x;
    const int b = blockIdx.x;
    if (b < CB) {
        int i = b * 256 + t;
        if (i < n4) {
            float4 v = x4[i];
            ushort4 o;
            o.x = f2bf(v.x); o.y = f2bf(v.y); o.z = f2bf(v.z); o.w = f2bf(v.w);
            hb[i] = o;
        }
    } else if (b < CB + 256) {
        int idx = (b - CB) * 256 + t;      // 4*128*128 = 65536 elems
        int i = idx >> 14;
        int rem = idx & 16383;
        int k = rem >> 7, c = rem & 127;
        Wt[(i << 14) + c * 128 + k] = f2bf(W[idx]);
    } else {
        h[t] = 0;
        __syncthreads();
        const int e0 = (b - CB - 256) * CHUNK;
        const int cnt = min(CHUNK, E - e0);
        for (int i = t; i < cnt; i += 256) atomicAdd(&h[ec[e0 + i] >> BSH], 1);
        __syncthreads();
        if (h[t]) atomicAdd(&bucketCnt[t], h[t]);
    }
}

// exclusive scan over 256 bucket counts -> bucketBase, globCursor
__global__ __launch_bounds__(256) void bucket_scan(const int* __restrict__ bucketCnt,
                                                   int* __restrict__ bucketBase,
                                                   int* __restrict__ globCursor) {
    __shared__ int s[256];
    const int t = threadIdx.x;
    int v = bucketCnt[t];
    s[t] = v; __syncthreads();
    for (int off = 1; off < 256; off <<= 1) {
        int x = (t >= off) ? s[t - off] : 0;
        __syncthreads();
        s[t] += x;
        __syncthreads();
    }
    int excl = s[t] - v;
    bucketBase[t] = excl;
    globCursor[t] = excl;
}

// scatter packed (r<<9 | c&511) into bucket-grouped array, LDS-staged
__global__ __launch_bounds__(256) void scatter_pairs(const int* __restrict__ er,
                                                     const int* __restrict__ ec, int E,
                                                     int* __restrict__ globCursor,
                                                     int* __restrict__ pairs) {
    __shared__ int h[256], lbase[256], cur[256], segd[256], s[256];
    __shared__ int stage[CHUNK];
    __shared__ unsigned char sb[CHUNK];
    const int t = threadIdx.x;
    const int e0 = blockIdx.x * CHUNK;
    const int cnt = min(CHUNK, E - e0);

    h[t] = 0;
    __syncthreads();
    for (int i = t; i < cnt; i += 256) atomicAdd(&h[ec[e0 + i] >> BSH], 1);
    __syncthreads();
    int v = h[t];
    s[t] = v; __syncthreads();
    for (int off = 1; off < 256; off <<= 1) {
        int x = (t >= off) ? s[t - off] : 0;
        __syncthreads();
        s[t] += x;
        __syncthreads();
    }
    lbase[t] = s[t] - v;
    cur[t] = s[t] - v;
    segd[t] = atomicAdd(&globCursor[t], v) - lbase[t];
    __syncthreads();
    for (int i = t; i < cnt; i += 256) {
        int c = ec[e0 + i];
        int b = c >> BSH;
        int p = atomicAdd(&cur[b], 1);
        stage[p] = (er[e0 + i] << BSH) | (c & 511);   // packed pair
        sb[p] = (unsigned char)b;
    }
    __syncthreads();
    for (int i = t; i < cnt; i += 256) {
        int b = sb[i];
        pairs[segd[b] + i] = stage[i];
    }
}

// one block per bucket. LDS hist+scan -> rowptr, dinv, slot fill. Unpadded.
__global__ __launch_bounds__(256) void fill_csr(const int* __restrict__ pairs,
                                                const int* __restrict__ bucketBase,
                                                const int* __restrict__ bucketCnt,
                                                int N, int E, int NBUCK,
                                                int* __restrict__ rowptr,
                                                float* __restrict__ dinv,
                                                int* __restrict__ srcs) {
    __shared__ int hist[512], lofs[512], s[256];
    const int t = threadIdx.x;
    const int b = blockIdx.x;
    const int c0 = b << BSH;
    const int base = bucketBase[b];
    const int cnt = bucketCnt[b];
    const int* pp = pairs + base;

    hist[t] = 0; hist[t + 256] = 0;
    __syncthreads();
    for (int i = t; i < cnt; i += 256) atomicAdd(&hist[pp[i] & 511], 1);
    __syncthreads();
    int a0 = hist[2 * t], a1 = hist[2 * t + 1];
    s[t] = a0 + a1; __syncthreads();
    for (int off = 1; off < 256; off <<= 1) {
        int x = (t >= off) ? s[t - off] : 0;
        __syncthreads();
        s[t] += x;
        __syncthreads();
    }
    int excl = s[t] - (a0 + a1);
    lofs[2 * t] = excl;
    lofs[2 * t + 1] = excl + a0;
    __syncthreads();
    const int nn = min(512, N - c0);
    for (int i = t; i < nn; i += 256) {
        rowptr[c0 + i] = base + lofs[i];
        dinv[c0 + i] = rsqrtf((float)hist[i] + 1.0f);
    }
    if (b == NBUCK - 1 && t == 0) rowptr[N] = E;
    __syncthreads();
    for (int i = t; i < cnt; i += 256) {
        int pr = pp[i];
        int p = atomicAdd(&lofs[pr & 511], 1);
        srcs[base + p] = pr >> BSH;
    }
}

// scale the bf16 x-cast by dinv in place (S = dinv * x):
// one uint4 (8 bf16) per thread, 16 uint4 per row.
__global__ __launch_bounds__(256) void scale_x(uint4* __restrict__ Hb0,
                                               const float* __restrict__ dinv,
                                               int nq) {                // nq = N*16
    int i = blockIdx.x * 256 + threadIdx.x;
    if (i >= nq) return;
    float dv = dinv[i >> 4];
    uint4 v = Hb0[i];
    unsigned int* p = (unsigned int*)&v;
#pragma unroll
    for (int k = 0; k < 4; ++k) {
        unsigned int d = p[k];
        unsigned short lo = f2bf(bf2f((unsigned short)(d & 0xFFFFu)) * dv);
        unsigned short hi = f2bf(bf2f((unsigned short)(d >> 16)) * dv);
        p[k] = ((unsigned int)hi << 16) | lo;
    }
    Hb0[i] = v;
}

// ---------------------------------------------------------------------------
// Fused layer: 256-thread block (4 waves) per 16-row tile.
// Phase A: 16 sixteen-lane groups (grp = wave*4+quad); group aggregates ONE
//   row (grp); lane owns one 16B chunk of the 256B row. Masked 8-edge
//   batch loop (best measured). Inputs pre-scaled S = dinv*h.
//   P = dinv[row]*(sum S + S[row]) -> bf16, xor-swizzled A-tile.
// Phase B: barrier; all 4 waves load the same A-frags; barrier; wave w
//   computes column-tiles ct = 2w, 2w+1 (disjoint out columns). Epilogue
//   folds bias+relu+output-dinv into the shared out tile (pitch OP);
//   barrier; coalesced 16B readback+stores (1 chunk/thread).
//   Layer 4 (writeDots): intra-wave shfl reduce + 4-wave LDS reduce.
// C/D: col=lane&15, row=(lane>>4)*4+reg (verified mapping).
// ---------------------------------------------------------------------------
__global__ __launch_bounds__(256, 4) void layer_fused(
        const int* __restrict__ rowptr, const int* __restrict__ srcs,
        const float* __restrict__ dinv, const unsigned short* __restrict__ H,
        const unsigned short* __restrict__ Wt, const float* __restrict__ bias,
        unsigned short* __restrict__ Hn, float* __restrict__ dots,
        const float* __restrict__ Wl, int N, int writeDots) {
    __shared__ __align__(16) unsigned short U[16 * OP];   // 4.25 KB
    const int tid = threadIdx.x;         // 0..255
    const int wave = tid >> 6;           // 0..3
    const int lane = tid & 63;
    const int row16 = lane & 15;
    const int quad = lane >> 4;          // 0..3
    const int grp = wave * 4 + quad;     // 0..15
    const int r0 = blockIdx.x * 16;
    const bf16x8* H8 = (const bf16x8*)H;     // 16 chunks (16B) per row
    const int gl = row16;                    // chunk index this lane owns

    // ---- phase A: each group aggregates ITS row into swizzled A-tile ----
    {
        const int rt = grp;              // local row 0..15
        const int row = r0 + rt;
        float acc[8] = {0.f, 0.f, 0.f, 0.f, 0.f, 0.f, 0.f, 0.f};
        float sn = 0.f;
        if (row < N) {
            sn = dinv[row];
            int j = rowptr[row];
            const int end = rowptr[row + 1];
            // self-loop term (pre-scaled)
            bf16x8 hv = H8[(size_t)row * 16 + gl];
#pragma unroll
            for (int k = 0; k < 8; ++k) acc[k] = bf2f((unsigned short)hv[k]);
            const int ne = end - j;
            const int nb = (ne + 7) >> 3;     // masked 8-edge batches
            if (nb > 0) {
                i32x4u sA0, sA1, sB0, sB1;
                {   // srcs(0); srcs(1) issued BEFORE h(0)
                    const i32x4u* sp = (const i32x4u*)(srcs + j);
                    sA0 = sp[0]; sA1 = sp[1];
                }
                if (nb > 1) {
                    const i32x4u* sp = (const i32x4u*)(srcs + j + 8);
                    sB0 = sp[0]; sB1 = sp[1];
                }
                bf16x8 hc[8], hn[8];
#pragma unroll
                for (int t = 0; t < 8; ++t) {       // issue h(0)
                    int idx = (t < 4) ? sA0[t] : sA1[t - 4];
                    int rr = (t < ne) ? idx : row;
                    hc[t] = H8[(size_t)rr * 16 + gl];
                }
#pragma unroll 1
                for (int b = 0; b < nb; ++b) {
                    if (b + 1 < nb) {
                        const int remn = ne - (b + 1) * 8;
                        int rn[8];
#pragma unroll
                        for (int t = 0; t < 8; ++t) {   // waits srcs(b+1) only
                            int idx = (t < 4) ? sB0[t] : sB1[t - 4];
                            rn[t] = (t < remn) ? idx : row;
                        }
                        if (b + 2 < nb) {               // srcs(b+2) BEFORE h(b+1)
                            const i32x4u* sp = (const i32x4u*)(srcs + j + (b + 2) * 8);
                            sB0 = sp[0]; sB1 = sp[1];
                        }
#pragma unroll
                        for (int t = 0; t < 8; ++t)     // issue h(b+1)
                            hn[t] = H8[(size_t)rn[t] * 16 + gl];
                    }
                    // consume h(b); weight from remaining count
                    const int rem = ne - b * 8;
#pragma unroll
                    for (int t = 0; t < 8; ++t) {
                        const float w = (t < rem) ? 1.f : 0.f;
#pragma unroll
                        for (int k = 0; k < 8; ++k)
                            acc[k] = fmaf(w, bf2f((unsigned short)hc[t][k]), acc[k]);
                    }
#pragma unroll
                    for (int t = 0; t < 8; ++t) hc[t] = hn[t];
                }
            }
        }
        // P row (bf16) -> swizzled A-tile; rows >= N become zeros (sn=0)
        bf16x8 o;
#pragma unroll
        for (int k = 0; k < 8; ++k) o[k] = (short)f2bf(sn * acc[k]);
        *(bf16x8*)(U + rt * 128 + ((gl ^ rt) << 3)) = o;
    }
    __syncthreads();

    // ---- phase B: all waves load the same A fragments ----
    bf16x8 a0[4];
#pragma unroll
    for (int kc = 0; kc < 4; ++kc) {
        const int ph = (kc * 4 + quad) ^ row16;
        a0[kc] = *(const bf16x8*)(U + row16 * 128 + ph * 8);
    }
    __syncthreads();   // U is now reused as the out tile (pitch OP)

    // dinv of output rows (pre-scale stored features); not needed for dots
    float dv[4];
    if (!writeDots) {
#pragma unroll
        for (int i = 0; i < 4; ++i) {
            int ra = r0 + quad * 4 + i;
            dv[i] = (ra < N) ? dinv[ra] : 0.f;
        }
    }

    // wave w handles column-tiles ct = 2w, 2w+1
    float rd[4] = {0.f, 0.f, 0.f, 0.f};
#pragma unroll
    for (int c = 0; c < 2; ++c) {
        const int ct = wave * 2 + c;
        const int col = ct * 16 + row16;
        const bf16x8* wc = (const bf16x8*)(Wt + (size_t)col * 128);
        f32x4 acc0 = {0.f, 0.f, 0.f, 0.f};
#pragma unroll
        for (int kc = 0; kc < 4; ++kc) {
            const bf16x8 wf = wc[kc * 4 + quad];
            acc0 = __builtin_amdgcn_mfma_f32_16x16x32_bf16(a0[kc], wf, acc0, 0, 0, 0);
        }
        const float bv = bias[col];
        if (writeDots) {
            const float wl = Wl[col];
#pragma unroll
            for (int i = 0; i < 4; ++i) rd[i] += fmaxf(acc0[i] + bv, 0.f) * wl;
        } else {
#pragma unroll
            for (int i = 0; i < 4; ++i)
                U[(quad * 4 + i) * OP + col] = f2bf(dv[i] * fmaxf(acc0[i] + bv, 0.f));
        }
    }

    if (writeDots) {
        // intra-wave: sum over the 16 cols of each ct (lanes of same quad)
#pragma unroll
        for (int m = 1; m < 16; m <<= 1)
#pragma unroll
            for (int i = 0; i < 4; ++i) rd[i] += __shfl_xor(rd[i], m, 64);
        // cross-wave: partials via LDS (U reused as float scratch)
        float* R = (float*)U;
        if (row16 == 0) {
#pragma unroll
            for (int i = 0; i < 4; ++i) R[wave * 16 + quad * 4 + i] = rd[i];
        }
        __syncthreads();
        if (tid < 16) dots[r0 + tid] = R[tid] + R[16 + tid] + R[32 + tid] + R[48 + tid];
    } else {
        __syncthreads();
        // coalesced readback + store: 256 16B chunks, 1 per thread
        {
            int row = tid >> 4, c8 = tid & 15;
            bf16x8 v = *(const bf16x8*)(U + row * OP + c8 * 8);
            *(bf16x8*)(Hn + (size_t)(r0 + row) * 128 + c8 * 8) = v;
        }
    }
}

// one block per graph: binary-search node range in sorted batch, mean, +bl
__global__ __launch_bounds__(256) void pool_graphs(const float* __restrict__ dots,
                                                   const int* __restrict__ batch, int N,
                                                   const float* __restrict__ bl,
                                                   float* __restrict__ out) {
    __shared__ int bounds[2];
    __shared__ float red[4];
    const int g = blockIdx.x;
    const int t = threadIdx.x;
    if (t < 2) {
        int key = g + t;             // lower_bound(batch, key)
        int lo = 0, hi = N;
        while (lo < hi) {
            int mid = (lo + hi) >> 1;
            if (batch[mid] < key) lo = mid + 1; else hi = mid;
        }
        bounds[t] = lo;
    }
    __syncthreads();
    const int lo = bounds[0], hi = bounds[1];
    float s = 0.f;
    for (int i = lo + t; i < hi; i += 256) s += dots[i];
#pragma unroll
    for (int off = 32; off > 0; off >>= 1) s += __shfl_down(s, off, 64);
    if ((t & 63) == 0) red[t >> 6] = s;
    __syncthreads();
    if (t == 0) {
        float tot = red[0] + red[1] + red[2] + red[3];
        int cnt = hi - lo;
        out[g] = tot / (float)(cnt > 0 ? cnt : 1) + bl[0];
    }
}

extern "C" void kernel_launch(void* const* d_in, const int* in_sizes, int n_in,
                              void* d_out, int out_size, void* d_ws, size_t ws_size,
                              hipStream_t stream) {
    const float* x     = (const float*)d_in[0];
    const int*   eidx  = (const int*)d_in[1];    // int32 (harness converts int64)
    const int*   batch = (const int*)d_in[2];
    const float* Ws    = (const float*)d_in[3];
    const float* bs    = (const float*)d_in[4];
    const float* Wl    = (const float*)d_in[5];
    const float* bl    = (const float*)d_in[6];
    (void)n_in; (void)out_size;

    const int N = in_sizes[0] / D;
    const int E = in_sizes[1] / 2;
    const int* er = eidx;       // sources
    const int* ec = eidx + E;   // targets
    const int NBUCK = (N + 511) >> BSH;          // 512-node buckets (<= 256)
    const int NCHUNK = (E + CHUNK - 1) / CHUNK;

    // ---- workspace carve ----
    const int Npad = (N + 127) & ~127;
    const size_t hBytes = (size_t)Npad * D * sizeof(unsigned short); // 25.6 MB bf16
    auto al = [](size_t v) { return (v + 255) & ~(size_t)255; };
    char* base = (char*)d_ws;
    size_t off = 0;

    unsigned short* Hb0 = (unsigned short*)base; off = al(hBytes);
    int* bucketCnt  = (int*)(base + off);
    int* globCursor = bucketCnt + 256;
    off = al(off + 512 * sizeof(int));
    int*   bucketBase = (int*)(base + off);  off = al(off + 256 * sizeof(int));
    float* dinv   = (float*)(base + off);    off = al(off + (size_t)Npad * sizeof(float));
    float* dots   = (float*)(base + off);    off = al(off + (size_t)Npad * sizeof(float));
    int*   rowptr = (int*)(base + off);      off = al(off + (size_t)(Npad + 64) * sizeof(int));
    int*   srcs   = (int*)(base + off);      off = al(off + ((size_t)E + 64) * sizeof(int));
    unsigned short* Wt = (unsigned short*)(base + off);   off = al(off + 4 * 128 * 128 * sizeof(unsigned short));

    // second bf16 buffer: in ws if it fits, else reuse x's 51.2 MB input buffer
    // (Npad*256B <= N*512B, so the alias stays in-bounds). pairs aliases Hb1:
    // CSR build completes before layer-1 gemm writes Hb1 (same stream).
    const bool twoBuf = ws_size >= off + hBytes;
    unsigned short* Hb1 = twoBuf ? (unsigned short*)(base + off)
                                 : (unsigned short*)d_in[0];
    int* pairs = (int*)Hb1;
    unsigned short* hb[2] = { Hb0, Hb1 };

    // ---- setup: memset bucketCnt; merged cast_x | cast_W | histogram ----
    hipMemsetAsync(bucketCnt, 0, 256 * sizeof(int), stream);
    const int n4 = N * D / 4;
    const int CB = (n4 + 255) / 256;
    setup_all<<<CB + 256 + NCHUNK, 256, 0, stream>>>((const float4*)x, (ushort4*)Hb0,
                                                     n4, CB, Ws, Wt, ec, E, bucketCnt);

    // ---- binned CSR build (once; reused by all 4 layers) ----
    bucket_scan<<<1, 256, 0, stream>>>(bucketCnt, bucketBase, globCursor);
    scatter_pairs<<<NCHUNK, 256, 0, stream>>>(er, ec, E, globCursor, pairs);
    fill_csr<<<NBUCK, 256, 0, stream>>>(pairs, bucketBase, bucketCnt, N, E, NBUCK,
                                        rowptr, dinv, srcs);
    // ---- pre-scale x-cast by dinv (S = dinv*x) ----
    const int nq = N * 16;                       // uint4 per row = 16
    scale_x<<<(nq + 255) / 256, 256, 0, stream>>>((uint4*)Hb0, dinv, nq);

    // ---- 4 fused layers: aggregate -> LDS A-tile -> MFMA (-> head dot) ----
    for (int i = 0; i < 4; ++i) {
        const unsigned short* Hc = hb[i & 1];
        unsigned short* Hn = hb[(i + 1) & 1];
        layer_fused<<<Npad / 16, 256, 0, stream>>>(rowptr, srcs, dinv, Hc,
                                                   Wt + (size_t)i * D * D,
                                                   bs + (size_t)i * D, Hn, dots, Wl,
                                                   N, (i == 3) ? 1 : 0);
    }

    // ---- mean pool (+bl) over fused per-node dots ----
    pool_graphs<<<NGRAPH, 256, 0, stream>>>(dots, batch, N, bl, (float*)d_out);
}